// Round 1
// baseline (232.085 us; speedup 1.0000x reference)
//
#include <hip/hip_runtime.h>

// GCN 3-layer forward, fp32 — Round 13: pos folded into scatter (9 dispatches).
//   Layers (proven, R11): gather-sum (node-parallel float4, 8-wide branch-free
//   over x8-padded lists, dummy=N -> zeroed row N) -> LDS GEMM -> epilogue.
//   Build: memset(cnt) -> deg_rank -> scan_partial -> scan_finish (bsum scan +
//   offset add + pad fill) -> scatter (8x dst-range partitioned, pos computed
//   inline) -> prescale (fused row-N zeroing).

#define FEAT 64
#define SCAN_B 1024
#define STILE 68   // s_tile stride: breaks 4-way LDS bank conflict on k-loop

typedef int v4i __attribute__((ext_vector_type(4)));

// ---------- CSR build ----------
// degree count; atomic return value = within-row rank of edge e.
__global__ void deg_rank_kernel(const int* __restrict__ dst, int* __restrict__ cnt,
                                int* __restrict__ rank, int E4) {
    int i = blockIdx.x * blockDim.x + threadIdx.x;
    if (i < E4) {
        v4i d = __builtin_nontemporal_load(((const v4i*)dst) + i);
        v4i r;
        r[0] = atomicAdd(&cnt[d[0]], 1);
        r[1] = atomicAdd(&cnt[d[1]], 1);
        r[2] = atomicAdd(&cnt[d[2]], 1);
        r[3] = atomicAdd(&cnt[d[3]], 1);
        __builtin_nontemporal_store(r, ((v4i*)rank) + i);
    }
}

// Pass 1: exclusive scan over counts PADDED to multiple of 8 -> rowptr
// (chunk-local), bsum. dinv from RAW count: rsqrt(1+cnt).
__global__ __launch_bounds__(SCAN_B) void scan_partial_kernel(
    const int* __restrict__ cnt, int* __restrict__ rowptr,
    int* __restrict__ bsum, float* __restrict__ dinv, int n) {
    __shared__ int wsum[SCAN_B / 64 + 1];
    const int tid  = threadIdx.x;
    const int lane = tid & 63;
    const int wid  = tid >> 6;
    const int i = blockIdx.x * SCAN_B + tid;

    int vr = (i < n) ? cnt[i] : 0;
    if (i < n) dinv[i] = rsqrtf((float)(1 + vr));
    int v = (vr + 7) & ~7;            // pad each list to multiple of 8
    int incl = v;
#pragma unroll
    for (int off = 1; off < 64; off <<= 1) {
        int t = __shfl_up(incl, off, 64);
        if (lane >= off) incl += t;
    }
    if (lane == 63) wsum[wid] = incl;
    __syncthreads();
    if (tid == 0) {
        int run = 0;
#pragma unroll
        for (int w = 0; w < SCAN_B / 64; ++w) { int t = wsum[w]; wsum[w] = run; run += t; }
        wsum[SCAN_B / 64] = run;
        bsum[blockIdx.x] = run;
    }
    __syncthreads();
    if (i < n) rowptr[i] = incl - v + wsum[wid];
}

// Pass 2 (fused): every block wave-scans bsum (nb<=64) to get its own offset,
// adds it, writes rowptr[n], and fills each list's padding slots with dummy.
__global__ __launch_bounds__(SCAN_B) void scan_finish_kernel(
    const int* __restrict__ cnt, int* __restrict__ rowptr,
    const int* __restrict__ bsum, int* __restrict__ col,
    int n, int nb, int dummy) {
    __shared__ int s_off, s_tot;
    const int tid = threadIdx.x;
    if (tid < 64) {
        int v = (tid < nb) ? bsum[tid] : 0;
        int incl = v;
#pragma unroll
        for (int off = 1; off < 64; off <<= 1) {
            int t = __shfl_up(incl, off, 64);
            if ((tid & 63) >= off) incl += t;
        }
        if (tid == (int)blockIdx.x) s_off = incl - v;  // exclusive offset
        if (tid == 63) s_tot = incl;                   // grand total
    }
    __syncthreads();
    const int i = blockIdx.x * SCAN_B + tid;
    if (i < n) {
        const int rp = rowptr[i] + s_off;
        rowptr[i] = rp;
        const int c = cnt[i];
        const int e = rp + ((c + 7) & ~7);
        for (int p = rp + c; p < e; ++p) col[p] = dummy;
    }
    if (i == 0) rowptr[n] = s_tot;
}

// dst-range-partitioned scatter with inline pos: q = blockIdx&7 owns dst nodes
// [q*qn, (q+1)*qn) -> a contiguous col region; only q's XCD dirties those
// lines (full-line writebacks). rowptr gather is L2-resident (200 KB).
__global__ void scatter_kernel(const int* __restrict__ src, const int* __restrict__ dst,
                               const int* __restrict__ rank, const int* __restrict__ rowptr,
                               int* __restrict__ col, int E4, int qn, int n) {
    const int q = blockIdx.x & 7;
    const int i = (blockIdx.x >> 3) * blockDim.x + threadIdx.x;
    const int nlo = q * qn;
    const int nhi = (nlo + qn < n) ? nlo + qn : n;
    if (i < E4) {
        v4i s = __builtin_nontemporal_load(((const v4i*)src) + i);
        v4i d = __builtin_nontemporal_load(((const v4i*)dst) + i);
        v4i r = __builtin_nontemporal_load(((const v4i*)rank) + i);
#pragma unroll
        for (int j = 0; j < 4; ++j) {
            if (d[j] >= nlo && d[j] < nhi) col[rowptr[d[j]] + r[j]] = s[j];
        }
    }
}

// P1[i] = x[i] * dinv[row]; tail block zeroes row N of P1 and P2 (dummy target).
__global__ void prescale_kernel(const float* __restrict__ x, const float* __restrict__ dinv,
                                float* __restrict__ P1, float* __restrict__ P2, int nq) {
    int i = blockIdx.x * blockDim.x + threadIdx.x;
    if (i < nq) {
        float d = dinv[i >> 4];
        float4 v = ((const float4*)x)[i];
        ((float4*)P1)[i] = make_float4(v.x * d, v.y * d, v.z * d, v.w * d);
    } else if (i < nq + 16) {
        const float4 z = make_float4(0.f, 0.f, 0.f, 0.f);
        ((float4*)P1)[i] = z;   // row N of P1
        ((float4*)P2)[i] = z;   // row N of P2
    }
}

// ---------- fused layer: gather-sum -> LDS -> GEMM -> bias/act ----------
// 16 nodes/block, 16 lanes/node (float4/lane). Lists padded to x8: branch-free
// 8-wide loop, col read as 2x int4, 8 float4 gathers in flight, 4 independent
// accumulators. Dummy entries hit zeroed row N. Input pre-scaled by dinv[src].
template<int INTER>
__global__ __launch_bounds__(256) void layer_kernel(
    const int* __restrict__ rowptr, const int* __restrict__ col,
    const float* __restrict__ dinv, const float* __restrict__ Xs,
    const float* __restrict__ W, const float* __restrict__ bias,
    float* __restrict__ out, int n) {
    __shared__ float w_lds[FEAT * FEAT];   // [k][c]
    __shared__ float s_tile[16 * STILE];   // [r][k], padded

    const int t = threadIdx.x;
#pragma unroll
    for (int i = 0; i < 4; ++i) {
        int idx = (i * 256 + t) * 4;
        *(float4*)&w_lds[idx] = *(const float4*)&W[idx];
    }
    __syncthreads();   // W visible; nothing else needs a barrier below

    const int r  = t >> 4;       // local node 0..15
    const int c4 = t & 15;       // float4 feature group
    const int g  = blockIdx.x * 16 + r;
    if (g >= n) return;
    const int f = c4 * 4;
    const float* __restrict__ Hf = Xs + f;

    // self-loop term (input pre-scaled)
    float4 a0 = *(const float4*)&Hf[(size_t)g * FEAT];
    float4 a1 = make_float4(0.f, 0.f, 0.f, 0.f);
    float4 a2 = make_float4(0.f, 0.f, 0.f, 0.f);
    float4 a3 = make_float4(0.f, 0.f, 0.f, 0.f);

    int p = rowptr[g];
    const int end = rowptr[g + 1];   // end - p is a multiple of 8

    for (; p < end; p += 8) {
        const v4i c0 = *(const v4i*)&col[p];
        const v4i c1 = *(const v4i*)&col[p + 4];
        const float4 h0 = *(const float4*)&Hf[(size_t)c0[0] * FEAT];
        const float4 h1 = *(const float4*)&Hf[(size_t)c0[1] * FEAT];
        const float4 h2 = *(const float4*)&Hf[(size_t)c0[2] * FEAT];
        const float4 h3 = *(const float4*)&Hf[(size_t)c0[3] * FEAT];
        const float4 h4 = *(const float4*)&Hf[(size_t)c1[0] * FEAT];
        const float4 h5 = *(const float4*)&Hf[(size_t)c1[1] * FEAT];
        const float4 h6 = *(const float4*)&Hf[(size_t)c1[2] * FEAT];
        const float4 h7 = *(const float4*)&Hf[(size_t)c1[3] * FEAT];
        a0.x += h0.x; a0.y += h0.y; a0.z += h0.z; a0.w += h0.w;
        a1.x += h1.x; a1.y += h1.y; a1.z += h1.z; a1.w += h1.w;
        a2.x += h2.x; a2.y += h2.y; a2.z += h2.z; a2.w += h2.w;
        a3.x += h3.x; a3.y += h3.y; a3.z += h3.z; a3.w += h3.w;
        a0.x += h4.x; a0.y += h4.y; a0.z += h4.z; a0.w += h4.w;
        a1.x += h5.x; a1.y += h5.y; a1.z += h5.z; a1.w += h5.w;
        a2.x += h6.x; a2.y += h6.y; a2.z += h6.z; a2.w += h6.w;
        a3.x += h7.x; a3.y += h7.y; a3.z += h7.z; a3.w += h7.w;
    }
    float4 S = make_float4((a0.x + a1.x) + (a2.x + a3.x),
                           (a0.y + a1.y) + (a2.y + a3.y),
                           (a0.z + a1.z) + (a2.z + a3.z),
                           (a0.w + a1.w) + (a2.w + a3.w));
    *(float4*)&s_tile[r * STILE + f] = S;
    // no __syncthreads: wave w reads only rows 4w..4w+3, which it wrote

    // in-block GEMM: T[r][f..f+3] = sum_k S[r][k] * W[k][f..f+3]
    float4 acc = make_float4(0.f, 0.f, 0.f, 0.f);
#pragma unroll
    for (int k = 0; k < FEAT; ++k) {
        const float sv = s_tile[r * STILE + k];
        const float4 wv = *(const float4*)&w_lds[k * FEAT + f];
        acc.x += sv * wv.x; acc.y += sv * wv.y;
        acc.z += sv * wv.z; acc.w += sv * wv.w;
    }

    const float dg = dinv[g];
    const float4 bv = *(const float4*)&bias[f];
    float4 o = make_float4(acc.x * dg + bv.x, acc.y * dg + bv.y,
                           acc.z * dg + bv.z, acc.w * dg + bv.w);
    if (INTER) {   // ReLU, then pre-scale for next layer's gather
        o.x = fmaxf(o.x, 0.f) * dg; o.y = fmaxf(o.y, 0.f) * dg;
        o.z = fmaxf(o.z, 0.f) * dg; o.w = fmaxf(o.w, 0.f) * dg;
    }
    *(float4*)&out[(size_t)g * FEAT + f] = o;
}

extern "C" void kernel_launch(void* const* d_in, const int* in_sizes, int n_in,
                              void* d_out, int out_size, void* d_ws, size_t ws_size,
                              hipStream_t stream) {
    const float* x  = (const float*)d_in[0];
    const int*   ei = (const int*)d_in[1];
    const float* W0 = (const float*)d_in[2];
    const float* b0 = (const float*)d_in[3];
    const float* W1 = (const float*)d_in[4];
    const float* b1 = (const float*)d_in[5];
    const float* W2 = (const float*)d_in[6];
    const float* b2 = (const float*)d_in[7];
    float* out = (float*)d_out;

    const int N = in_sizes[0] / FEAT;   // 50000
    const int E = in_sizes[1] / 2;      // 800000 (divisible by 4)
    const int* src = ei;
    const int* dst = ei + E;

    const int nbScan = (N + SCAN_B - 1) / SCAN_B;   // 49 (<= 64 for scan_finish)
    const int Ecap = E + 8 * N;                      // padded col capacity

    // workspace layout (64B-aligned regions)
    char* w = (char*)d_ws;
    auto take = [&](size_t bytes) { char* p = w; w += (bytes + 63) & ~(size_t)63; return p; };
    int*   cnt    = (int*)take(sizeof(int) * (size_t)N);
    int*   rowptr = (int*)take(sizeof(int) * (size_t)(N + 1));
    int*   bsum   = (int*)take(sizeof(int) * (size_t)(nbScan + 1));
    int*   col    = (int*)take(sizeof(int) * (size_t)Ecap);
    float* dinv   = (float*)take(sizeof(float) * (size_t)N);
    float* P1     = (float*)take(sizeof(float) * ((size_t)(N + 1) * FEAT));
    float* P2     = (float*)take(sizeof(float) * ((size_t)(N + 1) * FEAT));
    int*   rank = (int*)P2;   // alias: rank dead before layer-0 gemm writes P2

    const int tB = 256;
    const int E4  = E / 4;
    const int gE4 = (E4 + tB - 1) / tB;
    const int g16 = (N + 15) / 16;
    const int qn  = (N + 7) / 8;        // nodes per scatter partition
    const int nq  = N * FEAT / 4;
    const int gQ  = (nq + 16 + tB - 1) / tB;   // +16 float4s for row-N zeroing

    // CSR build (shared by all 3 layers)
    hipMemsetAsync(cnt, 0, sizeof(int) * (size_t)N, stream);
    deg_rank_kernel<<<gE4, tB, 0, stream>>>(dst, cnt, rank, E4);
    scan_partial_kernel<<<nbScan, SCAN_B, 0, stream>>>(cnt, rowptr, bsum, dinv, N);
    scan_finish_kernel<<<nbScan, SCAN_B, 0, stream>>>(cnt, rowptr, bsum, col, N, nbScan, N);
    scatter_kernel<<<gE4 * 8, tB, 0, stream>>>(src, dst, rank, rowptr, col, E4, qn, N);

    // prescale input into P1; zero row N of P1/P2 (dummy gather target)
    prescale_kernel<<<gQ, tB, 0, stream>>>(x, dinv, P1, P2, nq);

    // fused layers
    layer_kernel<1><<<g16, tB, 0, stream>>>(rowptr, col, dinv, P1, W0, b0, P2, N);
    layer_kernel<1><<<g16, tB, 0, stream>>>(rowptr, col, dinv, P2, W1, b1, P1, N);
    layer_kernel<0><<<g16, tB, 0, stream>>>(rowptr, col, dinv, P1, W2, b2, out, N);
}